// Round 1
// baseline (112.856 us; speedup 1.0000x reference)
//
#include <hip/hip_runtime.h>

#define NN 16384      // N nodes
#define NE 65536      // E edges
#define H  32
#define BB 32         // batch
#define NPER 512
#define NL 4

// ---- degree: deg[dst[e]] += 1 ----
__global__ void k_deg(const int* __restrict__ dst, float* __restrict__ deg) {
    int e = blockIdx.x * blockDim.x + threadIdx.x;
    if (e < NE) atomicAdd(&deg[dst[e]], 1.0f);
}

// ---- x = node_emb[x_nodes] ----
__global__ void k_embed(const int* __restrict__ x_nodes, const float* __restrict__ node_emb,
                        float* __restrict__ x) {
    int tid = blockIdx.x * blockDim.x + threadIdx.x;  // n*32+h
    if (tid < NN * H) {
        int n = tid >> 5, h = tid & 31;
        x[tid] = node_emb[x_nodes[n] * H + h];
    }
}

// ---- Wt[t][i][o] = sum_j relu(edge_emb[l][t][j]) * lin_w[l][j][i*32+o] + lin_b[l][i*32+o] ----
__global__ void k_weights(const float* __restrict__ edge_emb_l, const float* __restrict__ lin_w_l,
                          const float* __restrict__ lin_b_l, float* __restrict__ Wt) {
    int tid = blockIdx.x * blockDim.x + threadIdx.x;  // t*1024 + io
    if (tid < 16 * 1024) {
        int t = tid >> 10, io = tid & 1023;
        float acc = lin_b_l[io];
#pragma unroll
        for (int j = 0; j < 8; ++j) {
            float e = edge_emb_l[t * 8 + j];
            e = e > 0.f ? e : 0.f;
            acc += e * lin_w_l[j * 1024 + io];
        }
        Wt[tid] = acc;
    }
}

// ---- per-edge matvec + scatter add: agg[dst] += x[src] @ Wt[eattr] ----
// 32 lanes per edge (2 edges per wave64); lane o computes output element o.
__global__ void k_msg(const int* __restrict__ src, const int* __restrict__ dst,
                      const int* __restrict__ eattr, const float* __restrict__ x,
                      const float* __restrict__ Wt, float* __restrict__ agg) {
    int tid = blockIdx.x * blockDim.x + threadIdx.x;
    int e = tid >> 5;
    int o = tid & 31;
    if (e >= NE) return;
    int s = src[e], d = dst[e], t = eattr[e];
    float xv = x[s * H + o];                 // lane o holds x[src][o]
    const float* __restrict__ W = Wt + t * 1024;
    int base = threadIdx.x & 32;             // which half of the wave64
    float acc = 0.f;
#pragma unroll
    for (int i = 0; i < H; ++i) {
        float xi = __shfl(xv, base + i);     // broadcast x[src][i] within half-wave
        acc += xi * W[i * H + o];            // coalesced: 32 lanes read consecutive
    }
    atomicAdd(&agg[d * H + o], acc);
}

// ---- x_new = agg/denom + x @ root_w + conv_b, optional relu ----
__global__ void k_update(const float* __restrict__ x, const float* __restrict__ agg,
                         const float* __restrict__ deg, const float* __restrict__ root_w_l,
                         const float* __restrict__ conv_b_l, float* __restrict__ xout,
                         int do_relu) {
    int tid = blockIdx.x * blockDim.x + threadIdx.x;  // n*32+o
    if (tid >= NN * H) return;
    int n = tid >> 5, o = tid & 31;
    float xv = x[tid];
    int base = threadIdx.x & 32;
    float acc = conv_b_l[o];
#pragma unroll
    for (int i = 0; i < H; ++i) {
        float xi = __shfl(xv, base + i);
        acc += xi * root_w_l[i * H + o];
    }
    float dg = deg[n];
    dg = dg < 1.f ? 1.f : dg;
    float v = agg[tid] / dg + acc;
    if (do_relu) v = v > 0.f ? v : 0.f;
    xout[tid] = v;
}

// ---- readout: one thread per output element (B x 128) ----
__global__ void k_final(const float* __restrict__ x, const int* __restrict__ metal_idx,
                        const int* __restrict__ loop_edge, const int* __restrict__ loop_pair,
                        const float* __restrict__ f_w, const float* __restrict__ f_b,
                        float* __restrict__ out) {
    int tid = blockIdx.x * blockDim.x + threadIdx.x;
    if (tid >= BB * 128) return;
    int b = tid >> 7, j = tid & 127;
    int mg = metal_idx[b] + b * NPER;
    const float* __restrict__ xm = x + mg * H;
    int p0, p1;
    if (j < 64) {
        p0 = loop_edge[(b * 64 + j) * 2];
        p1 = loop_edge[(b * 64 + j) * 2 + 1];
    } else {
        int j2 = j - 64;
        p0 = loop_pair[(b * 64 + j2) * 2];
        p1 = loop_pair[(b * 64 + j2) * 2 + 1];
    }
    const float* __restrict__ xs = x + (b * NPER + p0) * H;
    const float* __restrict__ xt = x + (b * NPER + p1) * H;
    float fh = f_b[0];
    float pp = 0.f;
#pragma unroll
    for (int h = 0; h < H; ++h) {
        float m = xm[h];
        fh += m * f_w[h];
        pp += m * (xs[h] + xt[h]) - xs[h] * xt[h];
    }
    out[tid] = (j < 64) ? (pp - fh) : (-pp);
}

extern "C" void kernel_launch(void* const* d_in, const int* in_sizes, int n_in,
                              void* d_out, int out_size, void* d_ws, size_t ws_size,
                              hipStream_t stream) {
    const int*   x_nodes    = (const int*)d_in[0];
    const int*   edge_index = (const int*)d_in[1];
    const int*   src        = edge_index;
    const int*   dst        = edge_index + NE;
    const int*   edge_attr  = (const int*)d_in[2];
    const int*   metal_idx  = (const int*)d_in[3];
    const int*   loop_edge  = (const int*)d_in[4];
    const int*   loop_pair  = (const int*)d_in[5];
    const float* node_emb   = (const float*)d_in[6];
    const float* edge_emb   = (const float*)d_in[7];
    const float* lin_w      = (const float*)d_in[8];
    const float* lin_b      = (const float*)d_in[9];
    const float* root_w     = (const float*)d_in[10];
    const float* conv_b     = (const float*)d_in[11];
    const float* f_w        = (const float*)d_in[12];
    const float* f_b        = (const float*)d_in[13];
    float* out = (float*)d_out;

    float* ws  = (float*)d_ws;
    float* xA  = ws;                  // N*H
    float* xB  = ws + NN * H;         // N*H
    float* deg = ws + 2 * NN * H;     // N
    float* Wt  = deg + NN;            // 16*1024

    hipMemsetAsync(deg, 0, NN * sizeof(float), stream);
    k_deg<<<NE / 256, 256, 0, stream>>>(dst, deg);
    k_embed<<<NN * H / 256, 256, 0, stream>>>(x_nodes, node_emb, xA);

    float* xin = xA;
    float* xout = xB;
    for (int l = 0; l < NL; ++l) {
        k_weights<<<16 * 1024 / 256, 256, 0, stream>>>(
            edge_emb + l * 16 * 8, lin_w + l * 8 * 1024, lin_b + l * 1024, Wt);
        hipMemsetAsync(xout, 0, NN * H * sizeof(float), stream);
        k_msg<<<(NE * 32) / 256, 256, 0, stream>>>(src, dst, edge_attr, xin, Wt, xout);
        k_update<<<NN * H / 256, 256, 0, stream>>>(
            xin, xout, deg, root_w + l * H * H, conv_b + l * H, xout, l < NL - 1 ? 1 : 0);
        float* tmp = xin; xin = xout; xout = tmp;
    }

    k_final<<<(BB * 128 + 255) / 256, 256, 0, stream>>>(
        xin, metal_idx, loop_edge, loop_pair, f_w, f_b, out);
}